// Round 11
// baseline (321.219 us; speedup 1.0000x reference)
//
#include <hip/hip_runtime.h>

typedef __attribute__((ext_vector_type(8))) short short8;
typedef __attribute__((ext_vector_type(4))) float f32x4;

#define NB 8
#define NP 64
#define NS 256
#define ND 256
#define LSTR 264   // LDS row stride (bf16): 528 B; b128 GEMM reads land evenly on 16B bank-slots

// round-to-nearest-even fp32 -> bf16 bits
__device__ __forceinline__ unsigned short f2bf(float f) {
    unsigned int u = __float_as_uint(f);
    u = (u + 0x7FFFu + ((u >> 16) & 1u)) >> 16;
    return (unsigned short)u;
}

// K0: permute w[p][s][t] (t = 64*jb + 16*j + c) -> wt[((p*256+s)*4 + jb)*64 + 4*c + j]
// so K1's epilogue lane c loads its 4 needed w values as ONE coalesced f32x4.
// wt lives in the WORKSPACE (round-6 lesson: d_out staging causes dirty-line churn).
__global__ __launch_bounds__(256) void k0_wt(
    const float* __restrict__ w, float* __restrict__ wt)
{
    const int o  = blockIdx.x * 256 + threadIdx.x;   // f32x4 output index
    const int c  = o & 15;
    const int jb = (o >> 4) & 3;
    const int ps = o >> 6;                           // p*256 + s
    const float* row = w + (size_t)ps * NS + 64 * jb + c;
    f32x4 v;
    v.x = row[0]; v.y = row[16]; v.z = row[32]; v.w = row[48];
    reinterpret_cast<f32x4*>(wt)[o] = v;
}

// K1: one wg (1024 thr = 16 waves) per (b,p). Full X[b,p] bf16 in LDS; wave wv
// owns score tile (ib=wv>>2, jb=wv&3) of scores = X X^T.
// LEVER UNDER TEST: staging split into 4 col-quarters interleaved with GEMM
// k-quarters. Between barriers a wave stages quarter q+1 (memory) then GEMMs
// quarter q (LDS/MFMA); waves de-sync so HBM and DS/MFMA overlap ACROSS waves
// with zero extra register pressure (64-AGPR acc leaves none: 64V+64A = 128 cap).
__global__ __launch_bounds__(1024, 4) void k1_gemm_red(
    const float* __restrict__ x, const float* __restrict__ wt,
    float* __restrict__ red, float* __restrict__ Sx, float* __restrict__ Sxx)
{
    __shared__ unsigned short Xl[NS * LSTR];   // 135168 B
    __shared__ float red_l[4][NS];             // 4096 B

    const int t    = threadIdx.x;
    const int lane = t & 63;
    const int wv   = t >> 6;                   // 0..15
    const int ib   = wv >> 2;                  // row block of this wave's tile
    const int jb   = wv & 3;                   // col block
    const int p    = blockIdx.x & 63;
    const int b    = blockIdx.x >> 6;

    const float* xb      = x + (size_t)(b * NP + p) * (NS * ND);
    const size_t rowbase = (size_t)(b * NP + p) * NS;

    const int u   = lane >> 4;                 // row subgroup (staging) / qd (GEMM)
    const int l16 = lane & 15;                 // col-in-group (staging) / c (GEMM)

    float a[4] = {0.f, 0.f, 0.f, 0.f};         // Sx partials; row = 16*(4j+u)+wv

    f32x4 acc[4][4] = {};

    // stage col-quarter q (cols [64q,64q+64)) of all 16 rows owned by this wave.
    // iter j: 4 rows (i=4j+u), 16-lane group loads 256 B contiguous per row.
    auto STAGE = [&](int q) {
        #pragma unroll
        for (int j = 0; j < 4; ++j) {
            const int row = 16 * (4 * j + u) + wv;
            f32x4 v = *reinterpret_cast<const f32x4*>(
                xb + (size_t)row * ND + 64 * q + 4 * l16);
            float s = (v.x + v.y) + (v.z + v.w);
            #pragma unroll
            for (int off = 1; off < 16; off <<= 1) s += __shfl_xor(s, off, 64);
            a[j] += s;                          // partial row-sum for this quarter
            unsigned long long pk =
                  (unsigned long long)f2bf(v.x)
                | ((unsigned long long)f2bf(v.y) << 16)
                | ((unsigned long long)f2bf(v.z) << 32)
                | ((unsigned long long)f2bf(v.w) << 48);
            *reinterpret_cast<unsigned long long*>(
                &Xl[row * LSTR + 64 * q + 4 * l16]) = pk;
        }
    };

    // GEMM k-quarter g: k = [64g, 64g+64), 2 k-steps of 32
    auto GEMM = [&](int g) {
        #pragma unroll
        for (int kk = 0; kk < 2; ++kk) {
            const int kof = 64 * g + 32 * kk + u * 8;
            short8 afr[4], bfr[4];
            #pragma unroll
            for (int i = 0; i < 4; ++i)
                afr[i] = *reinterpret_cast<const short8*>(
                    &Xl[(64 * ib + 16 * i + l16) * LSTR + kof]);
            #pragma unroll
            for (int j = 0; j < 4; ++j)
                bfr[j] = *reinterpret_cast<const short8*>(
                    &Xl[(64 * jb + 16 * j + l16) * LSTR + kof]);
            #pragma unroll
            for (int i = 0; i < 4; ++i)
                #pragma unroll
                for (int j = 0; j < 4; ++j)
                    acc[i][j] = __builtin_amdgcn_mfma_f32_16x16x32_bf16(
                        afr[i], bfr[j], acc[i][j], 0, 0, 0);
        }
    };

    STAGE(0);
    __syncthreads();
    STAGE(1); GEMM(0);
    __syncthreads();
    STAGE(2); GEMM(1);
    __syncthreads();
    STAGE(3);
    if (l16 == 0) {                            // Sx complete after last quarter
        #pragma unroll
        for (int j = 0; j < 4; ++j)
            Sx[rowbase + 16 * (4 * j + u) + wv] = a[j];
    }
    GEMM(2);
    __syncthreads();
    GEMM(3);

    const int qd = u;
    const int c  = l16;

    // ---- Sxx = diag of X X^T: tiles with ib==jb, element needs 16i+4qd+r == 16j+c ----
    if (ib == jb && qd == (c >> 2)) {
        #pragma unroll
        for (int i = 0; i < 4; ++i)
            Sxx[rowbase + 64 * ib + 16 * i + c] = acc[i][i][c & 3];
    }

    // ---- weighted reduction over this tile's 64 cols; C layout col=c, row=4qd+reg.
    // wt layout gives the 4 j-terms for (row,jb,c) as one 16B-aligned f32x4. ----
    const float* wtp = wt + (size_t)p * (NS * NS);   // 256 floats per score-row
    #pragma unroll
    for (int i = 0; i < 4; ++i) {
        #pragma unroll
        for (int r = 0; r < 4; ++r) {
            const int rl = 16 * i + 4 * qd + r;       // local row in [0,64)
            const f32x4 wvec = *reinterpret_cast<const f32x4*>(
                wtp + (size_t)(64 * ib + rl) * NS + 64 * jb + 4 * c);
            float s = acc[i][0][r] * wvec.x + acc[i][1][r] * wvec.y
                    + acc[i][2][r] * wvec.z + acc[i][3][r] * wvec.w;
            #pragma unroll
            for (int off = 1; off < 16; off <<= 1)
                s += __shfl_xor(s, off, 64);
            if (c == 0) red_l[jb][64 * ib + rl] = s;  // disjoint per (jb,row): no race
        }
    }
    __syncthreads();
    if (t < NS)
        red[rowbase + t] =
            (red_l[0][t] + red_l[1][t] + red_l[2][t] + red_l[3][t]) * 0.0625f;
}

// K2: per-channel BN stats -> scale/bias
__global__ __launch_bounds__(256) void k2_stats(
    const float* __restrict__ red, const float* __restrict__ Sx,
    const float* __restrict__ Sxx, const float* __restrict__ gamma,
    const float* __restrict__ beta, float* __restrict__ sb)
{
    __shared__ float l1[256], l2[256];
    const int p = blockIdx.x;
    const int t = threadIdx.x;
    float sy = 0.f, syy = 0.f;
    for (int n = t; n < NB * NS; n += 256) {
        int bb = n >> 8, s = n & 255;
        size_t idx = (size_t)(bb * NP + p) * NS + s;
        float r = red[idx], aa = Sx[idx], q = Sxx[idx];
        sy  += aa + 256.f * r;
        syy += q + 2.f * r * aa + 256.f * r * r;
    }
    l1[t] = sy; l2[t] = syy;
    __syncthreads();
    for (int off = 128; off > 0; off >>= 1) {
        if (t < off) { l1[t] += l1[t + off]; l2[t] += l2[t + off]; }
        __syncthreads();
    }
    if (t == 0) {
        const float invN = 1.f / (float)(NB * NS * ND);
        float mean = l1[0] * invN;
        float var  = l2[0] * invN - mean * mean;
        float sc   = gamma[p] * rsqrtf(var + 1e-5f);
        sb[p]      = sc;
        sb[64 + p] = beta[p] - mean * sc;
    }
}

// K3: out = (x + red) * scale[p] + bias[p]; 4 float4/thread; nt stores keep L3 for x
__global__ __launch_bounds__(256) void k3_norm(
    const float* __restrict__ x, const float* __restrict__ red,
    const float* __restrict__ sb, float* __restrict__ out)
{
    const size_t f0 = (size_t)blockIdx.x * 1024 + threadIdx.x;
    #pragma unroll
    for (int k = 0; k < 4; ++k) {
        const size_t f = f0 + (size_t)k * 256;            // float4 index
        f32x4 v = reinterpret_cast<const f32x4*>(x)[f];
        const float r  = red[f >> 6];                     // row = elem>>8 = f>>6
        const int   pp = (int)((f >> 14) & 63);
        v = (v + r) * sb[pp] + sb[64 + pp];
        __builtin_nontemporal_store(v, reinterpret_cast<f32x4*>(out) + f);
    }
}

extern "C" void kernel_launch(void* const* d_in, const int* in_sizes, int n_in,
                              void* d_out, int out_size, void* d_ws, size_t ws_size,
                              hipStream_t stream)
{
    const float* x     = (const float*)d_in[0];
    const float* w     = (const float*)d_in[1];
    const float* gamma = (const float*)d_in[2];
    const float* beta  = (const float*)d_in[3];
    float* out = (float*)d_out;

    float* red = (float*)d_ws;                  // NB*NP*NS floats
    float* Sx  = red + (size_t)NB * NP * NS;
    float* Sxx = Sx  + (size_t)NB * NP * NS;
    float* sb  = Sxx + (size_t)NB * NP * NS;    // 128 floats (scale, bias)
    float* wt  = sb + 128;                      // NP*NS*NS floats (16.8 MB), in ws

    hipLaunchKernelGGL(k0_wt, dim3((NP * NS * NS) / (4 * 256)), dim3(256), 0, stream,
                       w, wt);
    hipLaunchKernelGGL(k1_gemm_red, dim3(NB * NP), dim3(1024), 0, stream,
                       x, wt, red, Sx, Sxx);
    hipLaunchKernelGGL(k2_stats, dim3(NP), dim3(256), 0, stream,
                       red, Sx, Sxx, gamma, beta, sb);
    hipLaunchKernelGGL(k3_norm, dim3((NB * NP * NS * ND) / (16 * 256)), dim3(256),
                       0, stream, x, red, sb, out);
}

// Round 13
// 315.298 us; speedup vs baseline: 1.0188x; 1.0188x over previous
//
#include <hip/hip_runtime.h>

typedef __attribute__((ext_vector_type(8))) short short8;
typedef __attribute__((ext_vector_type(4))) float f32x4;

#define NB 8
#define NP 64
#define NS 256
#define ND 256
#define LSTR 264   // LDS row stride (bf16): 528 B; GEMM b128 reads alias 2-way only (free)

// round-to-nearest-even fp32 -> bf16 bits
__device__ __forceinline__ unsigned short f2bf(float f) {
    unsigned int u = __float_as_uint(f);
    u = (u + 0x7FFFu + ((u >> 16) & 1u)) >> 16;
    return (unsigned short)u;
}

// K1: one wg (512 thr = 8 waves) per (b,p); full X[b,p] bf16 in LDS (1 block/CU).
// 2 waves/SIMD -> 256-VGPR budget: breaks the 128-reg wall that defeated rounds
// 7 (hoist) and 11 (interleave). Wave wid owns TWO tiles (ib=wid>>1, jb=2(wid&1)+tt)
// sharing A-fragments. Pipeline per column-quarter q:
//   ISSUE(q+1) 8 global loads -> regs;  GEMM(q) (loads stay in flight);
//   PACK(q+1) waitcnt+cvt+LDS write;    barrier.
__global__ __launch_bounds__(512, 2) void k1_gemm_red(
    const float* __restrict__ x, const float* __restrict__ w,
    float* __restrict__ red, float* __restrict__ Sx, float* __restrict__ Sxx)
{
    __shared__ unsigned short Xl[NS * LSTR];   // 135168 B
    __shared__ float red_l[4][NS];             // 4096 B

    const int t    = threadIdx.x;
    const int lane = t & 63;
    const int wid  = t >> 6;                   // 0..7
    const int ib   = wid >> 1;                 // shared row-block of both tiles
    const int jb0  = 2 * (wid & 1);            // first col-block (tt adds 0/1)
    const int p    = blockIdx.x & 63;
    const int b    = blockIdx.x >> 6;

    const float* xb      = x + (size_t)(b * NP + p) * (NS * ND);
    const size_t rowbase = (size_t)(b * NP + p) * NS;

    const int u   = lane >> 4;                 // 0..3: row subgroup / qd
    const int l16 = lane & 15;                 // 0..15: col-in-group / c

    f32x4 ld[8];                               // in-flight staging (32 VGPR)
    float a[8] = {0,0,0,0,0,0,0,0};            // Sx partials, rows 32*wid+4*j+u
    f32x4 acc[2][4][4] = {};                   // two tiles: 128 regs

    // issue 8 independent loads for col-quarter q (rows 32*wid..+31, 256B/row-grp)
    auto ISSUE = [&](int q) {
        #pragma unroll
        for (int j = 0; j < 8; ++j) {
            const int row = 32 * wid + 4 * j + u;
            ld[j] = *reinterpret_cast<const f32x4*>(
                xb + (size_t)row * ND + 64 * q + 4 * l16);
        }
    };
    // consume ld[]: row-sum partial + bf16 pack + LDS write
    auto PACK = [&](int q) {
        #pragma unroll
        for (int j = 0; j < 8; ++j) {
            const int row = 32 * wid + 4 * j + u;
            f32x4 v = ld[j];
            float s = (v.x + v.y) + (v.z + v.w);
            #pragma unroll
            for (int off = 1; off < 16; off <<= 1) s += __shfl_xor(s, off, 64);
            a[j] += s;
            unsigned long long pk =
                  (unsigned long long)f2bf(v.x)
                | ((unsigned long long)f2bf(v.y) << 16)
                | ((unsigned long long)f2bf(v.z) << 32)
                | ((unsigned long long)f2bf(v.w) << 48);
            *reinterpret_cast<unsigned long long*>(
                &Xl[row * LSTR + 64 * q + 4 * l16]) = pk;
        }
    };
    // GEMM k-quarter g for both tiles; A-fragments shared (12 reads/k-step)
    auto GEMM = [&](int g) {
        #pragma unroll
        for (int kk = 0; kk < 2; ++kk) {
            const int kof = 64 * g + 32 * kk + u * 8;
            short8 afr[4];
            #pragma unroll
            for (int i = 0; i < 4; ++i)
                afr[i] = *reinterpret_cast<const short8*>(
                    &Xl[(64 * ib + 16 * i + l16) * LSTR + kof]);
            #pragma unroll
            for (int tt = 0; tt < 2; ++tt) {
                short8 bfr[4];
                #pragma unroll
                for (int j = 0; j < 4; ++j)
                    bfr[j] = *reinterpret_cast<const short8*>(
                        &Xl[(64 * (jb0 + tt) + 16 * j + l16) * LSTR + kof]);
                #pragma unroll
                for (int i = 0; i < 4; ++i)
                    #pragma unroll
                    for (int j = 0; j < 4; ++j)
                        acc[tt][i][j] = __builtin_amdgcn_mfma_f32_16x16x32_bf16(
                            afr[i], bfr[j], acc[tt][i][j], 0, 0, 0);
            }
        }
    };

    ISSUE(0); PACK(0);
    __syncthreads();
    ISSUE(1); GEMM(0); PACK(1);
    __syncthreads();
    ISSUE(2); GEMM(1); PACK(2);
    __syncthreads();
    ISSUE(3); GEMM(2); PACK(3);
    if (l16 == 0) {
        #pragma unroll
        for (int j = 0; j < 8; ++j)
            Sx[rowbase + 32 * wid + 4 * j + u] = a[j];
    }
    __syncthreads();
    GEMM(3);

    // ---- Sxx = diag of X X^T: tile (ib,jb0+tt) diagonal when ib==jb0+tt ----
    #pragma unroll
    for (int tt = 0; tt < 2; ++tt) {
        if (ib == jb0 + tt && u == (l16 >> 2)) {
            #pragma unroll
            for (int i = 0; i < 4; ++i)
                Sxx[rowbase + 64 * ib + 16 * i + l16] = acc[tt][i][i][l16 & 3];
        }
    }

    // ---- weighted reduction; C layout col=l16, row=4u+r (verified round 0) ----
    const float* wp = w + (size_t)p * (NS * NS);
    #pragma unroll
    for (int tt = 0; tt < 2; ++tt) {
        const int jb = jb0 + tt;
        #pragma unroll
        for (int i = 0; i < 4; ++i) {
            #pragma unroll
            for (int r = 0; r < 4; ++r) {
                const int rl = 16 * i + 4 * u + r;        // local row in [0,64)
                const float* wrow = wp + (size_t)(64 * ib + rl) * NS + 64 * jb + l16;
                float s = acc[tt][i][0][r] * wrow[0]
                        + acc[tt][i][1][r] * wrow[16]
                        + acc[tt][i][2][r] * wrow[32]
                        + acc[tt][i][3][r] * wrow[48];
                #pragma unroll
                for (int off = 1; off < 16; off <<= 1)
                    s += __shfl_xor(s, off, 64);
                if (l16 == 0) red_l[jb][64 * ib + rl] = s; // disjoint (jb,row)
            }
        }
    }
    __syncthreads();
    if (t < NS)
        red[rowbase + t] =
            (red_l[0][t] + red_l[1][t] + red_l[2][t] + red_l[3][t]) * 0.0625f;
}

// K2: per-channel BN stats -> scale/bias
__global__ __launch_bounds__(256) void k2_stats(
    const float* __restrict__ red, const float* __restrict__ Sx,
    const float* __restrict__ Sxx, const float* __restrict__ gamma,
    const float* __restrict__ beta, float* __restrict__ sb)
{
    __shared__ float l1[256], l2[256];
    const int p = blockIdx.x;
    const int t = threadIdx.x;
    float sy = 0.f, syy = 0.f;
    for (int n = t; n < NB * NS; n += 256) {
        int bb = n >> 8, s = n & 255;
        size_t idx = (size_t)(bb * NP + p) * NS + s;
        float r = red[idx], aa = Sx[idx], q = Sxx[idx];
        sy  += aa + 256.f * r;
        syy += q + 2.f * r * aa + 256.f * r * r;
    }
    l1[t] = sy; l2[t] = syy;
    __syncthreads();
    for (int off = 128; off > 0; off >>= 1) {
        if (t < off) { l1[t] += l1[t + off]; l2[t] += l2[t + off]; }
        __syncthreads();
    }
    if (t == 0) {
        const float invN = 1.f / (float)(NB * NS * ND);
        float mean = l1[0] * invN;
        float var  = l2[0] * invN - mean * mean;
        float sc   = gamma[p] * rsqrtf(var + 1e-5f);
        sb[p]      = sc;
        sb[64 + p] = beta[p] - mean * sc;
    }
}

// K3: out = (x + red) * scale[p] + bias[p]; 4 float4/thread; nt stores keep L3 for x
__global__ __launch_bounds__(256) void k3_norm(
    const float* __restrict__ x, const float* __restrict__ red,
    const float* __restrict__ sb, float* __restrict__ out)
{
    const size_t f0 = (size_t)blockIdx.x * 1024 + threadIdx.x;
    #pragma unroll
    for (int k = 0; k < 4; ++k) {
        const size_t f = f0 + (size_t)k * 256;            // float4 index
        f32x4 v = reinterpret_cast<const f32x4*>(x)[f];
        const float r  = red[f >> 6];                     // row = elem>>8 = f>>6
        const int   pp = (int)((f >> 14) & 63);
        v = (v + r) * sb[pp] + sb[64 + pp];
        __builtin_nontemporal_store(v, reinterpret_cast<f32x4*>(out) + f);
    }
}

extern "C" void kernel_launch(void* const* d_in, const int* in_sizes, int n_in,
                              void* d_out, int out_size, void* d_ws, size_t ws_size,
                              hipStream_t stream)
{
    const float* x     = (const float*)d_in[0];
    const float* w     = (const float*)d_in[1];
    const float* gamma = (const float*)d_in[2];
    const float* beta  = (const float*)d_in[3];
    float* out = (float*)d_out;

    float* red = (float*)d_ws;                  // NB*NP*NS floats
    float* Sx  = red + (size_t)NB * NP * NS;
    float* Sxx = Sx  + (size_t)NB * NP * NS;
    float* sb  = Sxx + (size_t)NB * NP * NS;    // 128 floats (scale, bias)

    hipLaunchKernelGGL(k1_gemm_red, dim3(NB * NP), dim3(512), 0, stream,
                       x, w, red, Sx, Sxx);
    hipLaunchKernelGGL(k2_stats, dim3(NP), dim3(256), 0, stream,
                       red, Sx, Sxx, gamma, beta, sb);
    hipLaunchKernelGGL(k3_norm, dim3((NB * NP * NS * ND) / (16 * 256)), dim3(256),
                       0, stream, x, red, sb, out);
}

// Round 14
// 289.704 us; speedup vs baseline: 1.1088x; 1.0883x over previous
//
#include <hip/hip_runtime.h>

typedef __attribute__((ext_vector_type(8))) short short8;
typedef __attribute__((ext_vector_type(4))) float f32x4;

#define NB 8
#define NP 64
#define NS 256
#define ND 256
#define LSTR 264   // LDS row stride (bf16): 528 B, 16B-aligned, 2-way bank alias only (free)

// round-to-nearest-even fp32 -> bf16 bits
__device__ __forceinline__ unsigned short f2bf(float f) {
    unsigned int u = __float_as_uint(f);
    u = (u + 0x7FFFu + ((u >> 16) & 1u)) >> 16;
    return (unsigned short)u;
}

// K1 (round-0 core, measured 82 us, best of 7 structural variants tried r0-r13):
// one wg (1024 thr = 16 waves) per (b,p). Full X[b,p] bf16 in LDS; wave w owns
// score tile (ib=w>>2, jb=w&3) of the 256x256 scores = X X^T.
// red[s] = (1/16) sum_t w[p,s,t]*scores[s,t]; Sx during staging; Sxx = diag.
__global__ __launch_bounds__(1024, 4) void k1_gemm_red(
    const float* __restrict__ x, const float* __restrict__ w,
    float* __restrict__ red, float* __restrict__ Sx, float* __restrict__ Sxx)
{
    __shared__ unsigned short Xl[NS * LSTR];   // 135168 B
    __shared__ float red_l[4][NS];             // 4096 B

    const int t    = threadIdx.x;
    const int lane = t & 63;
    const int wv   = t >> 6;                   // 0..15
    const int ib   = wv >> 2;                  // row block of this wave's tile
    const int jb   = wv & 3;                   // col block
    const int p    = blockIdx.x & 63;
    const int b    = blockIdx.x >> 6;

    const float* xb      = x + (size_t)(b * NP + p) * (NS * ND);
    const size_t rowbase = (size_t)(b * NP + p) * NS;

    // ---- stage X fp32->bf16; wave w loads full row 16*i+w (coalesced 1KB/wave) ----
    #pragma unroll 4
    for (int i = 0; i < 16; ++i) {
        const int row = 16 * i + wv;
        f32x4 v = *reinterpret_cast<const f32x4*>(xb + row * ND + 4 * lane);
        float a = (v.x + v.y) + (v.z + v.w);
        #pragma unroll
        for (int off = 1; off < 64; off <<= 1) a += __shfl_xor(a, off, 64);
        if (lane == 0) Sx[rowbase + row] = a;
        unsigned long long pk =
              (unsigned long long)f2bf(v.x)
            | ((unsigned long long)f2bf(v.y) << 16)
            | ((unsigned long long)f2bf(v.z) << 32)
            | ((unsigned long long)f2bf(v.w) << 48);
        *reinterpret_cast<unsigned long long*>(&Xl[row * LSTR + 4 * lane]) = pk;
    }
    __syncthreads();

    const int qd = lane >> 4;
    const int c  = lane & 15;

    // ---- 64x64 tile GEMM out of LDS: 4x4 grid of 16x16x32 MFMAs, K=256 ----
    f32x4 acc[4][4] = {};
    #pragma unroll 2
    for (int k0 = 0; k0 < ND; k0 += 32) {
        const int kof = k0 + qd * 8;
        short8 afr[4], bfr[4];
        #pragma unroll
        for (int i = 0; i < 4; ++i)
            afr[i] = *reinterpret_cast<const short8*>(
                &Xl[(64 * ib + 16 * i + c) * LSTR + kof]);
        #pragma unroll
        for (int j = 0; j < 4; ++j)
            bfr[j] = *reinterpret_cast<const short8*>(
                &Xl[(64 * jb + 16 * j + c) * LSTR + kof]);
        #pragma unroll
        for (int i = 0; i < 4; ++i)
            #pragma unroll
            for (int j = 0; j < 4; ++j)
                acc[i][j] = __builtin_amdgcn_mfma_f32_16x16x32_bf16(
                    afr[i], bfr[j], acc[i][j], 0, 0, 0);
    }

    // ---- Sxx = diag of X X^T: tiles with ib==jb, element needs 16i+4qd+r == 16j+c ----
    if (ib == jb && qd == (c >> 2)) {
        #pragma unroll
        for (int i = 0; i < 4; ++i)
            Sxx[rowbase + 64 * ib + 16 * i + c] = acc[i][i][c & 3];
    }

    // ---- weighted reduction over this tile's 64 cols; C layout col=c, row=4qd+reg ----
    const float* wp = w + (size_t)p * (NS * NS);
    #pragma unroll
    for (int i = 0; i < 4; ++i) {
        #pragma unroll
        for (int r = 0; r < 4; ++r) {
            const int rl = 16 * i + 4 * qd + r;       // local row in [0,64)
            const float* wrow = wp + (size_t)(64 * ib + rl) * NS + 64 * jb + c;
            float s = acc[i][0][r] * wrow[0]
                    + acc[i][1][r] * wrow[16]
                    + acc[i][2][r] * wrow[32]
                    + acc[i][3][r] * wrow[48];
            #pragma unroll
            for (int off = 1; off < 16; off <<= 1)
                s += __shfl_xor(s, off, 64);
            if (c == 0) red_l[jb][64 * ib + rl] = s;  // disjoint per (jb,row): no race
        }
    }
    __syncthreads();
    if (t < NS)
        red[rowbase + t] =
            (red_l[0][t] + red_l[1][t] + red_l[2][t] + red_l[3][t]) * 0.0625f;
}

// K2: per-channel BN stats -> scale/bias
__global__ __launch_bounds__(256) void k2_stats(
    const float* __restrict__ red, const float* __restrict__ Sx,
    const float* __restrict__ Sxx, const float* __restrict__ gamma,
    const float* __restrict__ beta, float* __restrict__ sb)
{
    __shared__ float l1[256], l2[256];
    const int p = blockIdx.x;
    const int t = threadIdx.x;
    float sy = 0.f, syy = 0.f;
    for (int n = t; n < NB * NS; n += 256) {
        int bb = n >> 8, s = n & 255;
        size_t idx = (size_t)(bb * NP + p) * NS + s;
        float r = red[idx], a = Sx[idx], q = Sxx[idx];
        sy  += a + 256.f * r;
        syy += q + 2.f * r * a + 256.f * r * r;
    }
    l1[t] = sy; l2[t] = syy;
    __syncthreads();
    for (int off = 128; off > 0; off >>= 1) {
        if (t < off) { l1[t] += l1[t + off]; l2[t] += l2[t + off]; }
        __syncthreads();
    }
    if (t == 0) {
        const float invN = 1.f / (float)(NB * NS * ND);
        float mean = l1[0] * invN;
        float var  = l2[0] * invN - mean * mean;
        float sc   = gamma[p] * rsqrtf(var + 1e-5f);
        sb[p]      = sc;
        sb[64 + p] = beta[p] - mean * sc;
    }
}

// K3: out = (x + red) * scale[p] + bias[p]; 4 float4/thread.
// ROUND-14 LEVER: plain stores instead of __builtin_nontemporal_store.
// The nt rationale ("keep L3 for x") was stale; nt stores can bypass L2
// write-combining and throttle streaming writes. fillBuffer hits 6.8 TB/s
// with plain stores — if k3 was nt-throttled this recovers ~60+ us.
__global__ __launch_bounds__(256) void k3_norm(
    const float* __restrict__ x, const float* __restrict__ red,
    const float* __restrict__ sb, float* __restrict__ out)
{
    const size_t f0 = (size_t)blockIdx.x * 1024 + threadIdx.x;
    #pragma unroll
    for (int k = 0; k < 4; ++k) {
        const size_t f = f0 + (size_t)k * 256;            // float4 index
        f32x4 v = reinterpret_cast<const f32x4*>(x)[f];
        const float r  = red[f >> 6];                     // row = elem>>8 = f>>6
        const int   pp = (int)((f >> 14) & 63);
        v = (v + r) * sb[pp] + sb[64 + pp];
        reinterpret_cast<f32x4*>(out)[f] = v;
    }
}

extern "C" void kernel_launch(void* const* d_in, const int* in_sizes, int n_in,
                              void* d_out, int out_size, void* d_ws, size_t ws_size,
                              hipStream_t stream)
{
    const float* x     = (const float*)d_in[0];
    const float* w     = (const float*)d_in[1];
    const float* gamma = (const float*)d_in[2];
    const float* beta  = (const float*)d_in[3];
    float* out = (float*)d_out;

    float* red = (float*)d_ws;                  // NB*NP*NS floats
    float* Sx  = red + (size_t)NB * NP * NS;
    float* Sxx = Sx  + (size_t)NB * NP * NS;
    float* sb  = Sxx + (size_t)NB * NP * NS;    // 128 floats (scale, bias)

    hipLaunchKernelGGL(k1_gemm_red, dim3(NB * NP), dim3(1024), 0, stream,
                       x, w, red, Sx, Sxx);
    hipLaunchKernelGGL(k2_stats, dim3(NP), dim3(256), 0, stream,
                       red, Sx, Sxx, gamma, beta, sb);
    hipLaunchKernelGGL(k3_norm, dim3((NB * NP * NS * ND) / (16 * 256)), dim3(256),
                       0, stream, x, red, sb, out);
}